// Round 19
// baseline (331.506 us; speedup 1.0000x reference)
//
#include <hip/hip_runtime.h>
#include <hip/hip_bf16.h>
#include <math.h>

#define HEADS 8
#define HEAD_DIM 32
#define DIM 256
#define MLP_DIM 1024
#define NTOK 4096
#define BATCH 8
#define M_TOK (BATCH*NTOK)
#define CELL_DIM 15
#define PE_IN 3
#define UPD 12
#define HME ((size_t)M_TOK*32)   // elements per head-plane [tok][32]

typedef __attribute__((ext_vector_type(8))) short bf16x8;
typedef __attribute__((ext_vector_type(4))) float f32x4;

static __device__ __forceinline__ float bf2f(unsigned short u) {
    return __uint_as_float(((unsigned int)u) << 16);
}
static __device__ __forceinline__ unsigned short f2bf(float f) {
    __hip_bfloat16 h = __float2bfloat16(f);
    union { __hip_bfloat16 h; unsigned short u; } cv; cv.h = h; return cv.u;
}
static __device__ __forceinline__ void gload_lds16(const unsigned short* g, unsigned short* l) {
    __builtin_amdgcn_global_load_lds(
        (const __attribute__((address_space(1))) void*)g,
        (__attribute__((address_space(3))) void*)l, 16, 0, 0);
}
// sigmoid-form tanh-approx GELU (max abs err ~3e-4, fine vs 0.105 threshold)
static __device__ __forceinline__ float gelu_fast(float v) {
    return v / (1.f + __expf(-1.59576912f * (v + 0.044715f * v * v * v)));
}

// embed + fused LN1[0]: x(bf16) = cells@We + be + pe ; y = LN(x)
__global__ __launch_bounds__(256) void k_embed(const float* __restrict__ cells,
        const float* __restrict__ We, const float* __restrict__ be,
        const float* __restrict__ g, const float* __restrict__ bln,
        unsigned short* __restrict__ x, unsigned short* __restrict__ y) {
    __shared__ float red[8];
    int tok = blockIdx.x;
    int d = threadIdx.x;
    int b = tok >> 12, n = tok & 4095;
    const float* cb = cells + (size_t)b * CELL_DIM * NTOK + n;
    float acc = 0.f;
#pragma unroll
    for (int c = 0; c < CELL_DIM; ++c)
        acc += cb[c * NTOK] * We[c * DIM + d];
    int i = d >> 1;
    float freq = __expf(-0.03597789f * (float)(2 * i));   // exp(-ln(1e4)*2i/256)
    float ph = (float)n * freq;
    float pe = (d & 1) ? __cosf(ph) : __sinf(ph);
    float v = acc + be[d] + pe;
    x[(size_t)tok * DIM + d] = f2bf(v);
    float s = v, ss = v * v;
#pragma unroll
    for (int off = 32; off; off >>= 1) { s += __shfl_xor(s, off); ss += __shfl_xor(ss, off); }
    int wave = d >> 6, lane = d & 63;
    if (lane == 0) { red[wave] = s; red[4 + wave] = ss; }
    __syncthreads();
    float stot = red[0] + red[1] + red[2] + red[3];
    float sstot = red[4] + red[5] + red[6] + red[7];
    float mean = stot * (1.f / DIM);
    float rstd = rsqrtf(sstot * (1.f / DIM) - mean * mean + 1e-5f);
    y[(size_t)tok * DIM + d] = f2bf((v - mean) * rstd * g[d] + bln[d]);
}

// Transpose+convert weights to bf16 [N,K]; seg 8 builds WhT [16x256] (rows 12-15 zero)
__global__ __launch_bounds__(256) void k_prep(const float* __restrict__ Wqkv,
        const float* __restrict__ Wo, const float* __restrict__ W1,
        const float* __restrict__ W2, const float* __restrict__ Wh,
        unsigned short* __restrict__ wT) {
    int seg = blockIdx.y;
    int idx = blockIdx.x * 256 + threadIdx.x;
    if (seg == 8) {
        if (idx >= 16 * 256) return;
        int u = idx >> 8, k = idx & 255;
        wT[1572864 + idx] = (u < UPD) ? f2bf(Wh[(size_t)k * UPD + u]) : (unsigned short)0;
        return;
    }
    int l = seg >> 2, mat = seg & 3;
    const float* src; int kwSh, Nw; size_t ooff;
    switch (mat) {
        case 0: src = Wqkv + (size_t)l * 196608; kwSh = 8;  Nw = 768;  ooff = (size_t)l * 786432 + 0;      break;
        case 1: src = Wo   + (size_t)l * 65536;  kwSh = 8;  Nw = 256;  ooff = (size_t)l * 786432 + 196608; break;
        case 2: src = W1   + (size_t)l * 262144; kwSh = 8;  Nw = 1024; ooff = (size_t)l * 786432 + 262144; break;
        default:src = W2   + (size_t)l * 262144; kwSh = 10; Nw = 256;  ooff = (size_t)l * 786432 + 524288; break;
    }
    int Kw = 1 << kwSh;
    if (idx >= Kw * Nw) return;
    int n = idx >> kwSh, k = idx & (Kw - 1);
    wT[ooff + idx] = f2bf(src[(size_t)k * Nw + n]);
}

// 512-thread (8-wave), tile 128x256, wave owns 64m x 64n (acc[4][4]).
// 3-buffer distance-2 counted-vmcnt pipeline; uniform 3 loads/thread (1 A + 2 B).
// EPI1: gelu_fast(+bias) -> bf16 [M,N] ; EPI3: qkv scatter to head-planes.
template<int EPI, int KT>
__global__ __launch_bounds__(512, 4) void k_mgemm(const unsigned short* __restrict__ A,
        const unsigned short* __restrict__ BT, const float* __restrict__ bias,
        void* __restrict__ Cout, int M, int N, int NT) {
    __shared__ unsigned short As[3][128 * 32];   // 24 KB
    __shared__ unsigned short Bs[3][256 * 32];   // 48 KB
    int bid = blockIdx.x;
    int cpx = gridDim.x >> 3;                   // gridDim.x % 8 == 0
    int sb = (bid & 7) * cpx + (bid >> 3);
    int mt = sb / NT, nt = sb - mt * NT;
    int m0 = mt * 128, n0 = nt * 256;
    int t = threadIdx.x;
    int lane = t & 63, w = t >> 6;
    int wm = (w >> 2) * 64, wn = (w & 3) * 64;
    f32x4 acc[4][4] = {};
    int rA = t >> 2, cgA = (t & 3) ^ ((rA >> 1) & 3);
    const unsigned short* aBase = A + (size_t)(m0 + rA) * KT + cgA * 8;
    int rB0 = t >> 2, cgB0 = (t & 3) ^ ((rB0 >> 1) & 3);
    int c1 = t + 512;
    int rB1 = c1 >> 2, cgB1 = (c1 & 3) ^ ((rB1 >> 1) & 3);
    const unsigned short* b0Base = BT + (size_t)(n0 + rB0) * KT + cgB0 * 8;
    const unsigned short* b1Base = BT + (size_t)(n0 + rB1) * KT + cgB1 * 8;
    int fr = lane & 15, kb8 = lane >> 4;

    auto stage = [&](int buf, int k0) {          // uniform 3 loads / thread
        gload_lds16(aBase + k0,  &As[0][0] + buf * 4096 + t * 8);
        gload_lds16(b0Base + k0, &Bs[0][0] + buf * 8192 + t * 8);
        gload_lds16(b1Base + k0, &Bs[0][0] + buf * 8192 + 4096 + t * 8);
    };
    auto compute = [&](int buf) {
        const unsigned short* a = &As[0][0] + buf * 4096;
        const unsigned short* b = &Bs[0][0] + buf * 8192;
        bf16x8 af[4], bfv[4];
#pragma unroll
        for (int i = 0; i < 4; ++i) {
            int r_ = wm + i * 16 + fr;
            af[i] = *(const bf16x8*)&a[r_ * 32 + ((kb8 ^ ((r_ >> 1) & 3)) << 3)];
        }
#pragma unroll
        for (int j = 0; j < 4; ++j) {
            int r_ = wn + j * 16 + fr;
            bfv[j] = *(const bf16x8*)&b[r_ * 32 + ((kb8 ^ ((r_ >> 1) & 3)) << 3)];
        }
        __builtin_amdgcn_s_setprio(1);
#pragma unroll
        for (int i = 0; i < 4; ++i)
#pragma unroll
            for (int j = 0; j < 4; ++j)   // swapped: D[row=n][col=m]
                acc[i][j] = __builtin_amdgcn_mfma_f32_16x16x32_bf16(bfv[j], af[i], acc[i][j], 0, 0, 0);
        __builtin_amdgcn_s_setprio(0);
    };

    constexpr int NK = KT >> 5;                  // 8 for KT=256
    stage(0, 0);
    stage(1, 32);
    asm volatile("s_waitcnt vmcnt(3)" ::: "memory");   // stage0 landed; stage1 in flight
    __builtin_amdgcn_s_barrier();
    __builtin_amdgcn_sched_barrier(0);
#pragma unroll
    for (int k = 0; k < NK - 1; ++k) {
        if (k + 2 < NK) stage((k + 2) % 3, (k + 2) * 32);
        compute(k % 3);
        __builtin_amdgcn_sched_barrier(0);
        if (k + 2 < NK) asm volatile("s_waitcnt vmcnt(3)" ::: "memory");
        else            asm volatile("s_waitcnt vmcnt(0)" ::: "memory");
        __builtin_amdgcn_s_barrier();
        __builtin_amdgcn_sched_barrier(0);
    }
    compute((NK - 1) % 3);

    int mcol = lane & 15, nq = (lane >> 4) * 4;
#pragma unroll
    for (int i = 0; i < 4; ++i) {
        int m = m0 + wm + i * 16 + mcol;
#pragma unroll
        for (int j = 0; j < 4; ++j) {
            int ng = n0 + wn + j * 16 + nq;
            if (EPI == 3) {
                int type = ng >> 8, rem = ng & 255;
                ushort4 pk;
                pk.x = f2bf(acc[i][j][0]); pk.y = f2bf(acc[i][j][1]);
                pk.z = f2bf(acc[i][j][2]); pk.w = f2bf(acc[i][j][3]);
                *(ushort4*)((unsigned short*)Cout +
                    (size_t)(type * 8 + (rem >> 5)) * HME + (size_t)m * 32 + (rem & 31)) = pk;
            } else {
                float4 b4 = *(const float4*)&bias[ng];
                ushort4 pk;
                pk.x = f2bf(gelu_fast(acc[i][j][0] + b4.x));
                pk.y = f2bf(gelu_fast(acc[i][j][1] + b4.y));
                pk.z = f2bf(gelu_fast(acc[i][j][2] + b4.z));
                pk.w = f2bf(gelu_fast(acc[i][j][3] + b4.w));
                *(ushort4*)((unsigned short*)Cout + (size_t)m * N + ng) = pk;
            }
        }
    }
}

// 512-thread (8-wave) fused residual GEMM + LayerNorm, tile 128x256, bf16 residual.
// Wave owns 64m x 64n (acc[4][4]); uniform 3 loads/thread (1 A + 2 B); 3-buffer
// distance-2 counted-vmcnt. LN: per-row partials from 4 n-slice waves -> sred[128*4]
// (aliased into As after barrier). ALAYOUT 0: A[M,K] ; 1: A headwise [8][M][32].
// x(bf16) = A@BT + bias + x ; y = LN(x; g,b)
template<int ALAYOUT>
__global__ __launch_bounds__(512, 4) void k_mgemm_ln(const unsigned short* __restrict__ A,
        const unsigned short* __restrict__ BT, const float* __restrict__ bias,
        const float* __restrict__ g, const float* __restrict__ bln,
        unsigned short* __restrict__ x, unsigned short* __restrict__ y, int K) {
    __shared__ unsigned short As[3][128 * 32];   // 24 KB (re-used for reductions)
    __shared__ unsigned short Bs[3][256 * 32];   // 48 KB
    float* sred = (float*)&As[0][0];             // [128*4] = 2 KB
    float* ssred = sred + 512;                   // [128*4] = 2 KB
    float* msr = ssred + 512;                    // [128*2] = 1 KB
    int t = threadIdx.x;
    int lane = t & 63, w = t >> 6;
    int wm = (w >> 2) * 64, wn = (w & 3) * 64, wq = w & 3;
    int m0 = blockIdx.x * 128;
    int mcol = lane & 15, nq = (lane >> 4) * 4;

    f32x4 acc[4][4] = {};
    int rA = t >> 2, cgA = (t & 3) ^ ((rA >> 1) & 3);
    const unsigned short* aBase = (ALAYOUT == 0)
        ? A + (size_t)(m0 + rA) * K + cgA * 8
        : A + (size_t)(m0 + rA) * 32 + cgA * 8;
    int rB0 = t >> 2, cgB0 = (t & 3) ^ ((rB0 >> 1) & 3);
    int c1 = t + 512;
    int rB1 = c1 >> 2, cgB1 = (c1 & 3) ^ ((rB1 >> 1) & 3);
    const unsigned short* b0Base = BT + (size_t)rB0 * K + cgB0 * 8;
    const unsigned short* b1Base = BT + (size_t)rB1 * K + cgB1 * 8;
    int fr = lane & 15, kb8 = lane >> 4;

    auto stage = [&](int buf, int k0) {          // uniform 3 loads / thread
        const unsigned short* aSrc = (ALAYOUT == 0) ? aBase + k0 : aBase + (size_t)(k0 >> 5) * HME;
        gload_lds16(aSrc,        &As[0][0] + buf * 4096 + t * 8);
        gload_lds16(b0Base + k0, &Bs[0][0] + buf * 8192 + t * 8);
        gload_lds16(b1Base + k0, &Bs[0][0] + buf * 8192 + 4096 + t * 8);
    };
    auto compute = [&](int buf) {
        const unsigned short* a = &As[0][0] + buf * 4096;
        const unsigned short* b = &Bs[0][0] + buf * 8192;
        bf16x8 af[4], bfv[4];
#pragma unroll
        for (int i = 0; i < 4; ++i) {
            int r_ = wm + i * 16 + fr;
            af[i] = *(const bf16x8*)&a[r_ * 32 + ((kb8 ^ ((r_ >> 1) & 3)) << 3)];
        }
#pragma unroll
        for (int j = 0; j < 4; ++j) {
            int r_ = wn + j * 16 + fr;
            bfv[j] = *(const bf16x8*)&b[r_ * 32 + ((kb8 ^ ((r_ >> 1) & 3)) << 3)];
        }
        __builtin_amdgcn_s_setprio(1);
#pragma unroll
        for (int i = 0; i < 4; ++i)
#pragma unroll
            for (int j = 0; j < 4; ++j)          // swapped: D[row=n][col=m]
                acc[i][j] = __builtin_amdgcn_mfma_f32_16x16x32_bf16(bfv[j], af[i], acc[i][j], 0, 0, 0);
        __builtin_amdgcn_s_setprio(0);
    };

    int nk = K >> 5;
    stage(0, 0);
    stage(1, 32);
    asm volatile("s_waitcnt vmcnt(3)" ::: "memory");
    __builtin_amdgcn_s_barrier();
    __builtin_amdgcn_sched_barrier(0);
    int cur = 0;
    for (int k = 0; k < nk - 1; ++k) {
        int pre = k + 2;
        if (pre < nk) {
            int preBuf = cur + 2; if (preBuf >= 3) preBuf -= 3;
            stage(preBuf, pre * 32);
        }
        compute(cur);
        __builtin_amdgcn_sched_barrier(0);
        if (pre < nk) asm volatile("s_waitcnt vmcnt(3)" ::: "memory");
        else          asm volatile("s_waitcnt vmcnt(0)" ::: "memory");
        __builtin_amdgcn_s_barrier();
        __builtin_amdgcn_sched_barrier(0);
        ++cur; if (cur >= 3) cur -= 3;
    }
    compute(cur);
    __syncthreads();                             // before reusing As region for reductions

    // residual (bf16) + bias, per-row reduce (2 shuffles), cross-wave via LDS
#pragma unroll
    for (int i = 0; i < 4; ++i) {
        int gm = m0 + wm + i * 16 + mcol;
        float s = 0.f, ss = 0.f;
#pragma unroll
        for (int j = 0; j < 4; ++j) {
            int nb = wn + j * 16 + nq;
            ushort4 xr = *(const ushort4*)&x[(size_t)gm * DIM + nb];
            float4 b4 = *(const float4*)&bias[nb];
            acc[i][j][0] += b4.x + bf2f(xr.x);
            acc[i][j][1] += b4.y + bf2f(xr.y);
            acc[i][j][2] += b4.z + bf2f(xr.z);
            acc[i][j][3] += b4.w + bf2f(xr.w);
#pragma unroll
            for (int r = 0; r < 4; ++r) { float v = acc[i][j][r]; s += v; ss += v * v; }
        }
        s += __shfl_xor(s, 16); ss += __shfl_xor(ss, 16);
        s += __shfl_xor(s, 32); ss += __shfl_xor(ss, 32);
        if (lane < 16) {
            int row = wm + i * 16 + lane;
            sred[row * 4 + wq] = s;
            ssred[row * 4 + wq] = ss;
        }
    }
    __syncthreads();
    if (t < 128) {
        float s = sred[t * 4] + sred[t * 4 + 1] + sred[t * 4 + 2] + sred[t * 4 + 3];
        float ss = ssred[t * 4] + ssred[t * 4 + 1] + ssred[t * 4 + 2] + ssred[t * 4 + 3];
        float mean = s * (1.f / DIM);
        float var = ss * (1.f / DIM) - mean * mean;
        msr[t * 2] = mean;
        msr[t * 2 + 1] = rsqrtf(var + 1e-5f);
    }
    __syncthreads();
#pragma unroll
    for (int i = 0; i < 4; ++i) {
        int row = wm + i * 16 + mcol;
        int gm = m0 + row;
        float mean = msr[row * 2], rstd = msr[row * 2 + 1];
#pragma unroll
        for (int j = 0; j < 4; ++j) {
            int nb = wn + j * 16 + nq;
            float4 gv4 = *(const float4*)&g[nb];
            float4 bb4 = *(const float4*)&bln[nb];
            ushort4 xo;
            xo.x = f2bf(acc[i][j][0]); xo.y = f2bf(acc[i][j][1]);
            xo.z = f2bf(acc[i][j][2]); xo.w = f2bf(acc[i][j][3]);
            *(ushort4*)&x[(size_t)gm * DIM + nb] = xo;
            ushort4 yv;
            yv.x = f2bf((acc[i][j][0] - mean) * rstd * gv4.x + bb4.x);
            yv.y = f2bf((acc[i][j][1] - mean) * rstd * gv4.y + bb4.y);
            yv.z = f2bf((acc[i][j][2] - mean) * rstd * gv4.z + bb4.z);
            yv.w = f2bf((acc[i][j][3] - mean) * rstd * gv4.w + bb4.w);
            *(ushort4*)&y[(size_t)gm * DIM + nb] = yv;
        }
    }
}

// patch-LDS local 3x3 attention: block = (batch, head, 16x16 token patch).
// 18x18 halo K/V staged in LDS (40-elem padded slots, 16B-aligned), 9x reuse.
__global__ __launch_bounds__(256) void k_attn(const unsigned short* __restrict__ qkvH,
        unsigned short* __restrict__ attnH) {
    __shared__ unsigned short Ks[324 * 40];   // 25.9 KB
    __shared__ unsigned short Vs[324 * 40];   // 25.9 KB
    int bid = blockIdx.x;                     // 8b x 8h x 4pr x 4pc = 1024
    int b = bid >> 7, h = (bid >> 4) & 7, pr = (bid >> 2) & 3, pc = bid & 3;
    int t = threadIdx.x;
    int ty = t >> 4, tx = t & 15;
    const unsigned short* kplane = qkvH + (size_t)(8 + h) * HME;
    const unsigned short* vplane = qkvH + (size_t)(16 + h) * HME;

    // q for own token (global, coalesced) before the barrier
    int tok = (b << 12) + ((pr * 16 + ty) << 6) + (pc * 16 + tx);
    float q[32];
    {
        const uint4* u = (const uint4*)(qkvH + (size_t)h * HME + (size_t)tok * 32);
#pragma unroll
        for (int i = 0; i < 4; ++i) {
            uint4 x4 = u[i];
            unsigned wv[4] = {x4.x, x4.y, x4.z, x4.w};
#pragma unroll
            for (int wj = 0; wj < 4; ++wj) {
                q[i * 8 + wj * 2]     = __uint_as_float(wv[wj] << 16);
                q[i * 8 + wj * 2 + 1] = __uint_as_float(wv[wj] & 0xffff0000u);
            }
        }
    }
    // stage 18x18 halo (wrap-around) K and V
    for (int s = t; s < 324; s += 256) {
        int sr = s / 18, sc = s - sr * 18;
        int gr = (pr * 16 + sr - 1) & 63, gc = (pc * 16 + sc - 1) & 63;
        size_t nt = ((size_t)b << 12) + (gr << 6) + gc;
        const uint4* ksrc = (const uint4*)(kplane + nt * 32);
        const uint4* vsrc = (const uint4*)(vplane + nt * 32);
#pragma unroll
        for (int i = 0; i < 4; ++i) {
            *(uint4*)&Ks[s * 40 + i * 8] = ksrc[i];
            *(uint4*)&Vs[s * 40 + i * 8] = vsrc[i];
        }
    }
    __syncthreads();

    float dots[9];
    int slots[9];
#pragma unroll
    for (int ki = 0; ki < 3; ++ki)
#pragma unroll
        for (int kj = 0; kj < 3; ++kj) {
            int slot = (ty + ki) * 18 + (tx + kj);
            slots[ki * 3 + kj] = slot;
            const unsigned short* kp = &Ks[slot * 40];
            float acc = 0.f;
#pragma unroll
            for (int i = 0; i < 4; ++i) {
                uint4 x4 = *(const uint4*)(kp + i * 8);
                unsigned wv[4] = {x4.x, x4.y, x4.z, x4.w};
#pragma unroll
                for (int wj = 0; wj < 4; ++wj) {
                    acc += __uint_as_float(wv[wj] << 16)         * q[i * 8 + wj * 2];
                    acc += __uint_as_float(wv[wj] & 0xffff0000u) * q[i * 8 + wj * 2 + 1];
                }
            }
            dots[ki * 3 + kj] = acc * 0.17677669529f;
        }
    float m = dots[0];
#pragma unroll
    for (int j = 1; j < 9; ++j) m = fmaxf(m, dots[j]);
    float sum = 0.f;
#pragma unroll
    for (int j = 0; j < 9; ++j) { dots[j] = __expf(dots[j] - m); sum += dots[j]; }
    float inv = 1.f / sum;
    float o[32] = {};
#pragma unroll
    for (int j = 0; j < 9; ++j) {
        float wgt = dots[j] * inv;
        const unsigned short* vp = &Vs[slots[j] * 40];
#pragma unroll
        for (int i = 0; i < 4; ++i) {
            uint4 x4 = *(const uint4*)(vp + i * 8);
            unsigned wv[4] = {x4.x, x4.y, x4.z, x4.w};
#pragma unroll
            for (int wj = 0; wj < 4; ++wj) {
                o[i * 8 + wj * 2]     += wgt * __uint_as_float(wv[wj] << 16);
                o[i * 8 + wj * 2 + 1] += wgt * __uint_as_float(wv[wj] & 0xffff0000u);
            }
        }
    }
    uint4 st[4];
    unsigned* sw = (unsigned*)st;
#pragma unroll
    for (int i = 0; i < 16; ++i)
        sw[i] = (unsigned)f2bf(o[2 * i]) | ((unsigned)f2bf(o[2 * i + 1]) << 16);
    uint4* od = (uint4*)(attnH + (size_t)h * HME + (size_t)tok * 32);
#pragma unroll
    for (int i = 0; i < 4; ++i) od[i] = st[i];
}

// head GEMV via MFMA: Cg[32768,16] = y[32768,256] @ WhT[16,256]^T
__global__ __launch_bounds__(256) void k_headgemv(const unsigned short* __restrict__ y,
        const unsigned short* __restrict__ WhT, float* __restrict__ Cg) {
    int t = threadIdx.x, lane = t & 63, w = t >> 6;
    int m0 = blockIdx.x * 64 + w * 16;
    int fr = lane & 15, kb = (lane >> 4) * 8;
    f32x4 acc = {};
    const unsigned short* aRow = y + (size_t)(m0 + fr) * DIM + kb;
    const unsigned short* bRow = WhT + (size_t)fr * DIM + kb;
#pragma unroll
    for (int k0 = 0; k0 < DIM; k0 += 32) {
        bf16x8 a = *(const bf16x8*)(aRow + k0);
        bf16x8 bfr = *(const bf16x8*)(bRow + k0);
        acc = __builtin_amdgcn_mfma_f32_16x16x32_bf16(a, bfr, acc, 0, 0, 0);
    }
    int col = lane & 15, rowq = (lane >> 4) * 4;
#pragma unroll
    for (int r = 0; r < 4; ++r)
        Cg[(size_t)(m0 + rowq + r) * 16 + col] = acc[r];
}

// out[b,c,n] = cells[b,c,n] + (c>=3 ? Cg[tok,c-3] + bh[c-3] : 0)
__global__ __launch_bounds__(256) void k_assemble(const float* __restrict__ cells,
        const float* __restrict__ Cg, const float* __restrict__ bh,
        float* __restrict__ outp) {
    int idx = blockIdx.x * 256 + threadIdx.x;
    int total = BATCH * CELL_DIM * (NTOK / 4);
    if (idx >= total) return;
    int n4 = idx & 1023;
    int c = (idx >> 10) % CELL_DIM;
    int b = idx / (CELL_DIM * 1024);
    size_t ci = ((size_t)b * CELL_DIM + c) * NTOK + n4 * 4;
    float4 o = *(const float4*)(cells + ci);
    if (c >= PE_IN) {
        int u = c - PE_IN;
        float bias = bh[u];
        size_t tok = (size_t)b * NTOK + n4 * 4;
        o.x += Cg[(tok + 0) * 16 + u] + bias;
        o.y += Cg[(tok + 1) * 16 + u] + bias;
        o.z += Cg[(tok + 2) * 16 + u] + bias;
        o.w += Cg[(tok + 3) * 16 + u] + bias;
    }
    *(float4*)(outp + ci) = o;
}

extern "C" void kernel_launch(void* const* d_in, const int* in_sizes, int n_in,
                              void* d_out, int out_size, void* d_ws, size_t ws_size,
                              hipStream_t stream) {
    const float* cells = (const float*)d_in[0];
    const float* We    = (const float*)d_in[1];
    const float* be    = (const float*)d_in[2];
    const float* ln1_g = (const float*)d_in[3];
    const float* ln1_b = (const float*)d_in[4];
    const float* Wqkv  = (const float*)d_in[5];
    const float* Wo    = (const float*)d_in[6];
    const float* bo    = (const float*)d_in[7];
    const float* ln2_g = (const float*)d_in[8];
    const float* ln2_b = (const float*)d_in[9];
    const float* W1    = (const float*)d_in[10];
    const float* b1    = (const float*)d_in[11];
    const float* W2    = (const float*)d_in[12];
    const float* b2    = (const float*)d_in[13];
    const float* lnh_g = (const float*)d_in[14];
    const float* lnh_b = (const float*)d_in[15];
    const float* Wh    = (const float*)d_in[16];
    const float* bh    = (const float*)d_in[17];
    float* outp = (float*)d_out;

    char* ws = (char*)d_ws;
    unsigned short* x = (unsigned short*)ws;                      // 16.8 MB bf16 residual
    unsigned short* y = (unsigned short*)(ws + 33554432);         // 16.8 MB bf16 LN-out
    unsigned short* scratch = (unsigned short*)(ws + 50331648);   // 67.1 MB: qkvH+attnH / hidden / Cg
    unsigned short* wT = (unsigned short*)(ws + 117440512);       // 3 MB + 8KB transposed weights
    unsigned short* qkvH  = scratch;                              // [3][8][M][32] = 50.3 MB
    unsigned short* attnH = scratch + 24 * HME;                   // [8][M][32]   = 16.8 MB
    unsigned short* hidden = scratch;                             // [M][1024] = 67.1 MB (qkv dead by mlp1)
    float* Cg = (float*)scratch;                                  // reuse after last mlp2

    k_prep<<<dim3(1024, 9), 256, 0, stream>>>(Wqkv, Wo, W1, W2, Wh, wT);
    k_embed<<<M_TOK, 256, 0, stream>>>(cells, We, be, ln1_g, ln1_b, x, y);
    for (int l = 0; l < 2; ++l) {
        const unsigned short* wL = wT + (size_t)l * 786432;
        const float* gN = (l == 0) ? ln1_g + DIM : lnh_g;
        const float* bN = (l == 0) ? ln1_b + DIM : lnh_b;
        k_mgemm<3, 256><<<768, 512, 0, stream>>>(
            y, wL + 0, nullptr, qkvH, M_TOK, 768, 3);
        k_attn<<<1024, 256, 0, stream>>>(qkvH, attnH);
        k_mgemm_ln<1><<<M_TOK / 128, 512, 0, stream>>>(
            attnH, wL + 196608, bo + l * DIM, ln2_g + l * DIM, ln2_b + l * DIM, x, y, DIM);
        k_mgemm<1, 256><<<1024, 512, 0, stream>>>(
            y, wL + 262144, b1 + l * MLP_DIM, hidden, M_TOK, MLP_DIM, 4);
        k_mgemm_ln<0><<<M_TOK / 128, 512, 0, stream>>>(
            hidden, wL + 524288, b2 + l * DIM, gN, bN, x, y, MLP_DIM);
    }
    k_headgemv<<<M_TOK / 64, 256, 0, stream>>>(y, wT + 1572864, Cg);
    k_assemble<<<(BATCH * CELL_DIM * (NTOK / 4) + 255) / 256, 256, 0, stream>>>(cells, Cg, bh, outp);
}

// Round 20
// 321.141 us; speedup vs baseline: 1.0323x; 1.0323x over previous
//
#include <hip/hip_runtime.h>
#include <hip/hip_bf16.h>
#include <math.h>

#define HEADS 8
#define HEAD_DIM 32
#define DIM 256
#define MLP_DIM 1024
#define NTOK 4096
#define BATCH 8
#define M_TOK (BATCH*NTOK)
#define CELL_DIM 15
#define PE_IN 3
#define UPD 12
#define HME ((size_t)M_TOK*32)   // elements per head-plane [tok][32]

typedef __attribute__((ext_vector_type(8))) short bf16x8;
typedef __attribute__((ext_vector_type(4))) float f32x4;

static __device__ __forceinline__ float bf2f(unsigned short u) {
    return __uint_as_float(((unsigned int)u) << 16);
}
static __device__ __forceinline__ unsigned short f2bf(float f) {
    __hip_bfloat16 h = __float2bfloat16(f);
    union { __hip_bfloat16 h; unsigned short u; } cv; cv.h = h; return cv.u;
}
static __device__ __forceinline__ void gload_lds16(const unsigned short* g, unsigned short* l) {
    __builtin_amdgcn_global_load_lds(
        (const __attribute__((address_space(1))) void*)g,
        (__attribute__((address_space(3))) void*)l, 16, 0, 0);
}
// sigmoid-form tanh-approx GELU (max abs err ~3e-4, fine vs 0.105 threshold)
static __device__ __forceinline__ float gelu_fast(float v) {
    return v / (1.f + __expf(-1.59576912f * (v + 0.044715f * v * v * v)));
}

// wave-per-token embed + fused LN1[0]: x(bf16) = cells@We + be + pe ; y = LN(x)
// 4 tokens/block; lane owns 4 consecutive dims. cells reads wave-uniform.
__global__ __launch_bounds__(256) void k_embed(const float* __restrict__ cells,
        const float* __restrict__ We, const float* __restrict__ be,
        const float* __restrict__ g, const float* __restrict__ bln,
        unsigned short* __restrict__ x, unsigned short* __restrict__ y) {
    int wave = threadIdx.x >> 6, lane = threadIdx.x & 63;
    int tok = blockIdx.x * 4 + wave;
    int b = tok >> 12, n = tok & 4095;
    const float* cb = cells + (size_t)b * CELL_DIM * NTOK + n;
    float cv[CELL_DIM];
#pragma unroll
    for (int c = 0; c < CELL_DIM; ++c) cv[c] = cb[c * NTOK];
    int d0 = lane * 4;
    float v[4] = {};
#pragma unroll
    for (int c = 0; c < CELL_DIM; ++c) {
        float4 w4 = *(const float4*)&We[c * DIM + d0];
        v[0] += cv[c] * w4.x; v[1] += cv[c] * w4.y;
        v[2] += cv[c] * w4.z; v[3] += cv[c] * w4.w;
    }
    float4 be4 = *(const float4*)&be[d0];
    float bev[4] = {be4.x, be4.y, be4.z, be4.w};
#pragma unroll
    for (int r = 0; r < 4; ++r) {
        int d = d0 + r;
        float freq = __expf(-0.03597789f * (float)(d & ~1));
        float ph = (float)n * freq;
        float pe = (d & 1) ? __cosf(ph) : __sinf(ph);
        v[r] += bev[r] + pe;
    }
    ushort4 xo;
    xo.x = f2bf(v[0]); xo.y = f2bf(v[1]); xo.z = f2bf(v[2]); xo.w = f2bf(v[3]);
    *(ushort4*)&x[(size_t)tok * DIM + d0] = xo;
    float s = v[0] + v[1] + v[2] + v[3];
    float ss = v[0]*v[0] + v[1]*v[1] + v[2]*v[2] + v[3]*v[3];
#pragma unroll
    for (int off = 32; off; off >>= 1) { s += __shfl_xor(s, off); ss += __shfl_xor(ss, off); }
    float mean = s * (1.f / DIM);
    float rstd = rsqrtf(ss * (1.f / DIM) - mean * mean + 1e-5f);
    float4 g4 = *(const float4*)&g[d0];
    float4 bb4 = *(const float4*)&bln[d0];
    float gv[4] = {g4.x, g4.y, g4.z, g4.w};
    float bbv[4] = {bb4.x, bb4.y, bb4.z, bb4.w};
    ushort4 yo;
    yo.x = f2bf((v[0] - mean) * rstd * gv[0] + bbv[0]);
    yo.y = f2bf((v[1] - mean) * rstd * gv[1] + bbv[1]);
    yo.z = f2bf((v[2] - mean) * rstd * gv[2] + bbv[2]);
    yo.w = f2bf((v[3] - mean) * rstd * gv[3] + bbv[3]);
    *(ushort4*)&y[(size_t)tok * DIM + d0] = yo;
}

// Transpose+convert weights to bf16 [N,K]; seg 8 builds WhT [16x256] (rows 12-15 zero)
__global__ __launch_bounds__(256) void k_prep(const float* __restrict__ Wqkv,
        const float* __restrict__ Wo, const float* __restrict__ W1,
        const float* __restrict__ W2, const float* __restrict__ Wh,
        unsigned short* __restrict__ wT) {
    int seg = blockIdx.y;
    int idx = blockIdx.x * 256 + threadIdx.x;
    if (seg == 8) {
        if (idx >= 16 * 256) return;
        int u = idx >> 8, k = idx & 255;
        wT[1572864 + idx] = (u < UPD) ? f2bf(Wh[(size_t)k * UPD + u]) : (unsigned short)0;
        return;
    }
    int l = seg >> 2, mat = seg & 3;
    const float* src; int kwSh, Nw; size_t ooff;
    switch (mat) {
        case 0: src = Wqkv + (size_t)l * 196608; kwSh = 8;  Nw = 768;  ooff = (size_t)l * 786432 + 0;      break;
        case 1: src = Wo   + (size_t)l * 65536;  kwSh = 8;  Nw = 256;  ooff = (size_t)l * 786432 + 196608; break;
        case 2: src = W1   + (size_t)l * 262144; kwSh = 8;  Nw = 1024; ooff = (size_t)l * 786432 + 262144; break;
        default:src = W2   + (size_t)l * 262144; kwSh = 10; Nw = 256;  ooff = (size_t)l * 786432 + 524288; break;
    }
    int Kw = 1 << kwSh;
    if (idx >= Kw * Nw) return;
    int n = idx >> kwSh, k = idx & (Kw - 1);
    wT[ooff + idx] = f2bf(src[(size_t)k * Nw + n]);
}

// 512-thread (8-wave), tile 128x256, wave owns 64m x 64n (acc[4][4]).
// 3-buffer distance-2 counted-vmcnt pipeline; uniform 3 loads/thread (1 A + 2 B).
// EPI1: gelu_fast(+bias) -> bf16 [M,N] ; EPI3: qkv scatter to head-planes.
template<int EPI, int KT>
__global__ __launch_bounds__(512, 4) void k_mgemm(const unsigned short* __restrict__ A,
        const unsigned short* __restrict__ BT, const float* __restrict__ bias,
        void* __restrict__ Cout, int M, int N, int NT) {
    __shared__ unsigned short As[3][128 * 32];   // 24 KB
    __shared__ unsigned short Bs[3][256 * 32];   // 48 KB
    int bid = blockIdx.x;
    int cpx = gridDim.x >> 3;                   // gridDim.x % 8 == 0
    int sb = (bid & 7) * cpx + (bid >> 3);
    int mt = sb / NT, nt = sb - mt * NT;
    int m0 = mt * 128, n0 = nt * 256;
    int t = threadIdx.x;
    int lane = t & 63, w = t >> 6;
    int wm = (w >> 2) * 64, wn = (w & 3) * 64;
    f32x4 acc[4][4] = {};
    int rA = t >> 2, cgA = (t & 3) ^ ((rA >> 1) & 3);
    const unsigned short* aBase = A + (size_t)(m0 + rA) * KT + cgA * 8;
    int rB0 = t >> 2, cgB0 = (t & 3) ^ ((rB0 >> 1) & 3);
    int c1 = t + 512;
    int rB1 = c1 >> 2, cgB1 = (c1 & 3) ^ ((rB1 >> 1) & 3);
    const unsigned short* b0Base = BT + (size_t)(n0 + rB0) * KT + cgB0 * 8;
    const unsigned short* b1Base = BT + (size_t)(n0 + rB1) * KT + cgB1 * 8;
    int fr = lane & 15, kb8 = lane >> 4;

    auto stage = [&](int buf, int k0) {          // uniform 3 loads / thread
        gload_lds16(aBase + k0,  &As[0][0] + buf * 4096 + t * 8);
        gload_lds16(b0Base + k0, &Bs[0][0] + buf * 8192 + t * 8);
        gload_lds16(b1Base + k0, &Bs[0][0] + buf * 8192 + 4096 + t * 8);
    };
    auto compute = [&](int buf) {
        const unsigned short* a = &As[0][0] + buf * 4096;
        const unsigned short* b = &Bs[0][0] + buf * 8192;
        bf16x8 af[4], bfv[4];
#pragma unroll
        for (int i = 0; i < 4; ++i) {
            int r_ = wm + i * 16 + fr;
            af[i] = *(const bf16x8*)&a[r_ * 32 + ((kb8 ^ ((r_ >> 1) & 3)) << 3)];
        }
#pragma unroll
        for (int j = 0; j < 4; ++j) {
            int r_ = wn + j * 16 + fr;
            bfv[j] = *(const bf16x8*)&b[r_ * 32 + ((kb8 ^ ((r_ >> 1) & 3)) << 3)];
        }
        __builtin_amdgcn_s_setprio(1);
#pragma unroll
        for (int i = 0; i < 4; ++i)
#pragma unroll
            for (int j = 0; j < 4; ++j)   // swapped: D[row=n][col=m]
                acc[i][j] = __builtin_amdgcn_mfma_f32_16x16x32_bf16(bfv[j], af[i], acc[i][j], 0, 0, 0);
        __builtin_amdgcn_s_setprio(0);
    };

    constexpr int NK = KT >> 5;                  // 8 for KT=256
    stage(0, 0);
    stage(1, 32);
    asm volatile("s_waitcnt vmcnt(3)" ::: "memory");   // stage0 landed; stage1 in flight
    __builtin_amdgcn_s_barrier();
    __builtin_amdgcn_sched_barrier(0);
#pragma unroll
    for (int k = 0; k < NK - 1; ++k) {
        if (k + 2 < NK) stage((k + 2) % 3, (k + 2) * 32);
        compute(k % 3);
        __builtin_amdgcn_sched_barrier(0);
        if (k + 2 < NK) asm volatile("s_waitcnt vmcnt(3)" ::: "memory");
        else            asm volatile("s_waitcnt vmcnt(0)" ::: "memory");
        __builtin_amdgcn_s_barrier();
        __builtin_amdgcn_sched_barrier(0);
    }
    compute((NK - 1) % 3);

    int mcol = lane & 15, nq = (lane >> 4) * 4;
#pragma unroll
    for (int i = 0; i < 4; ++i) {
        int m = m0 + wm + i * 16 + mcol;
#pragma unroll
        for (int j = 0; j < 4; ++j) {
            int ng = n0 + wn + j * 16 + nq;
            if (EPI == 3) {
                int type = ng >> 8, rem = ng & 255;
                ushort4 pk;
                pk.x = f2bf(acc[i][j][0]); pk.y = f2bf(acc[i][j][1]);
                pk.z = f2bf(acc[i][j][2]); pk.w = f2bf(acc[i][j][3]);
                *(ushort4*)((unsigned short*)Cout +
                    (size_t)(type * 8 + (rem >> 5)) * HME + (size_t)m * 32 + (rem & 31)) = pk;
            } else {
                float4 b4 = *(const float4*)&bias[ng];
                ushort4 pk;
                pk.x = f2bf(gelu_fast(acc[i][j][0] + b4.x));
                pk.y = f2bf(gelu_fast(acc[i][j][1] + b4.y));
                pk.z = f2bf(gelu_fast(acc[i][j][2] + b4.z));
                pk.w = f2bf(gelu_fast(acc[i][j][3] + b4.w));
                *(ushort4*)((unsigned short*)Cout + (size_t)m * N + ng) = pk;
            }
        }
    }
}

// 512-thread (8-wave) fused residual GEMM + LayerNorm, bf16 residual stream.
// Tile 64x256; wave owns 32 n-cols (acc[4][2]). 3-buffer distance-2; uniform
// 3 loads/thread. Reduction arrays alias As (barrier before reuse).
// ALAYOUT 0: A[M,K] row-major ; 1: A headwise [8][M][32] (K=256)
// x(bf16) = A@BT + bias + x ; y = LN(x; g,b)
template<int ALAYOUT>
__global__ __launch_bounds__(512, 4) void k_mgemm_ln(const unsigned short* __restrict__ A,
        const unsigned short* __restrict__ BT, const float* __restrict__ bias,
        const float* __restrict__ g, const float* __restrict__ bln,
        unsigned short* __restrict__ x, unsigned short* __restrict__ y, int K) {
    __shared__ unsigned short As[3][64 * 32];    // 12 KB (re-used for reductions)
    __shared__ unsigned short Bs[3][256 * 32];   // 48 KB
    float* sred = (float*)&As[0][0];             // [64*8] = 2 KB
    float* ssred = sred + 512;                   // [64*8] = 2 KB
    float* msr = ssred + 512;                    // [64*2] = 0.5 KB
    int t = threadIdx.x;
    int lane = t & 63, w = t >> 6;               // 8 waves, wave owns n-slice w*32
    int wn = w * 32;
    int m0 = blockIdx.x * 64;
    int mloc = lane & 15, nq = (lane >> 4) * 4;

    // prefetch residual x (bf16, ushort4 = 4 elems); issued first -> oldest in vmcnt
    ushort4 xres[4][2];
#pragma unroll
    for (int i = 0; i < 4; ++i) {
        int gm = m0 + i * 16 + mloc;
#pragma unroll
        for (int j = 0; j < 2; ++j)
            xres[i][j] = *(const ushort4*)&x[(size_t)gm * DIM + wn + j * 16 + nq];
    }
    __builtin_amdgcn_sched_barrier(0);           // pin xres loads before stage loads

    f32x4 acc[4][2] = {};
    int rB0 = t >> 2, cgB0 = (t & 3) ^ ((rB0 >> 1) & 3);
    int c1 = t + 512;
    int rB1 = c1 >> 2, cgB1 = (c1 & 3) ^ ((rB1 >> 1) & 3);
    int tA = t & 255;
    int rA = tA >> 2, cgA = (tA & 3) ^ ((rA >> 1) & 3);
    const unsigned short* aBase = (ALAYOUT == 0)
        ? A + (size_t)(m0 + rA) * K + cgA * 8
        : A + (size_t)(m0 + rA) * 32 + cgA * 8;
    const unsigned short* b0Base = BT + (size_t)rB0 * K + cgB0 * 8;
    const unsigned short* b1Base = BT + (size_t)rB1 * K + cgB1 * 8;
    int fr = lane & 15, kb8 = lane >> 4;

    auto stage = [&](int buf, int k0) {          // uniform 3 loads / thread
        unsigned short* as_ = &As[0][0] + buf * 2048;
        unsigned short* bs_ = &Bs[0][0] + buf * 8192;
        gload_lds16(b0Base + k0, bs_ + t * 8);
        gload_lds16(b1Base + k0, bs_ + 4096 + t * 8);
        if (t < 256) {
            const unsigned short* aSrc = (ALAYOUT == 0) ? aBase + k0 : aBase + (size_t)(k0 >> 5) * HME;
            gload_lds16(aSrc, as_ + tA * 8);
        } else {
            gload_lds16(b0Base + k0, bs_ + t * 8);   // benign dup (same addr, same data)
        }
    };
    auto compute = [&](int buf) {
        const unsigned short* as_ = &As[0][0] + buf * 2048;
        const unsigned short* bs_ = &Bs[0][0] + buf * 8192;
        bf16x8 af[4], bfv[2];
#pragma unroll
        for (int i = 0; i < 4; ++i) {
            int r_ = i * 16 + fr;
            af[i] = *(const bf16x8*)&as_[r_ * 32 + ((kb8 ^ ((r_ >> 1) & 3)) << 3)];
        }
#pragma unroll
        for (int j = 0; j < 2; ++j) {
            int rl = wn + j * 16 + fr;           // global B row 0..255
            bfv[j] = *(const bf16x8*)&bs_[rl * 32 + ((kb8 ^ ((rl >> 1) & 3)) << 3)];
        }
        __builtin_amdgcn_s_setprio(1);
#pragma unroll
        for (int i = 0; i < 4; ++i)
#pragma unroll
            for (int j = 0; j < 2; ++j)          // swapped: D[row=n][col=m]
                acc[i][j] = __builtin_amdgcn_mfma_f32_16x16x32_bf16(bfv[j], af[i], acc[i][j], 0, 0, 0);
        __builtin_amdgcn_s_setprio(0);
    };

    int nk = K >> 5;
    stage(0, 0);
    stage(1, 32);
    asm volatile("s_waitcnt vmcnt(3)" ::: "memory");   // xres+stage0 retired, stage1 in flight
    __builtin_amdgcn_s_barrier();
    __builtin_amdgcn_sched_barrier(0);
    int cur = 0;
    for (int k = 0; k < nk - 1; ++k) {
        int pre = k + 2;
        if (pre < nk) {
            int preBuf = cur + 2; if (preBuf >= 3) preBuf -= 3;
            stage(preBuf, pre * 32);
        }
        compute(cur);
        __builtin_amdgcn_sched_barrier(0);
        if (pre < nk) asm volatile("s_waitcnt vmcnt(3)" ::: "memory");
        else          asm volatile("s_waitcnt vmcnt(0)" ::: "memory");
        __builtin_amdgcn_s_barrier();
        __builtin_amdgcn_sched_barrier(0);
        ++cur; if (cur >= 3) cur -= 3;
    }
    compute(cur);
    __syncthreads();                             // before reusing As region for reductions

    // bias + prefetched residual (bf16 unpack), per-row reduce, cross-wave via LDS
#pragma unroll
    for (int i = 0; i < 4; ++i) {
        float s = 0.f, ss = 0.f;
#pragma unroll
        for (int j = 0; j < 2; ++j) {
            int nb = wn + j * 16 + nq;
            float4 b4 = *(const float4*)&bias[nb];
            acc[i][j][0] += b4.x + bf2f(xres[i][j].x);
            acc[i][j][1] += b4.y + bf2f(xres[i][j].y);
            acc[i][j][2] += b4.z + bf2f(xres[i][j].z);
            acc[i][j][3] += b4.w + bf2f(xres[i][j].w);
#pragma unroll
            for (int r = 0; r < 4; ++r) { float v = acc[i][j][r]; s += v; ss += v * v; }
        }
        s += __shfl_xor(s, 16); ss += __shfl_xor(ss, 16);
        s += __shfl_xor(s, 32); ss += __shfl_xor(ss, 32);
        if (lane < 16) {
            int row = i * 16 + lane;
            sred[row * 8 + w] = s;
            ssred[row * 8 + w] = ss;
        }
    }
    __syncthreads();
    if (t < 64) {
        float s = 0.f, ss = 0.f;
#pragma unroll
        for (int q = 0; q < 8; ++q) { s += sred[t * 8 + q]; ss += ssred[t * 8 + q]; }
        float mean = s * (1.f / DIM);
        float var = ss * (1.f / DIM) - mean * mean;
        msr[t * 2] = mean;
        msr[t * 2 + 1] = rsqrtf(var + 1e-5f);
    }
    __syncthreads();
#pragma unroll
    for (int i = 0; i < 4; ++i) {
        int row = i * 16 + mloc;
        int gm = m0 + row;
        float mean = msr[row * 2], rstd = msr[row * 2 + 1];
#pragma unroll
        for (int j = 0; j < 2; ++j) {
            int nb = wn + j * 16 + nq;
            float4 gv4 = *(const float4*)&g[nb];
            float4 bb4 = *(const float4*)&bln[nb];
            ushort4 xo;
            xo.x = f2bf(acc[i][j][0]); xo.y = f2bf(acc[i][j][1]);
            xo.z = f2bf(acc[i][j][2]); xo.w = f2bf(acc[i][j][3]);
            *(ushort4*)&x[(size_t)gm * DIM + nb] = xo;
            ushort4 yv;
            yv.x = f2bf((acc[i][j][0] - mean) * rstd * gv4.x + bb4.x);
            yv.y = f2bf((acc[i][j][1] - mean) * rstd * gv4.y + bb4.y);
            yv.z = f2bf((acc[i][j][2] - mean) * rstd * gv4.z + bb4.z);
            yv.w = f2bf((acc[i][j][3] - mean) * rstd * gv4.w + bb4.w);
            *(ushort4*)&y[(size_t)gm * DIM + nb] = yv;
        }
    }
}

// patch-LDS local 3x3 attention: block = (batch, head, 16x16 token patch).
// 18x18 halo K/V staged in LDS (40-elem padded slots, 16B-aligned), 9x reuse.
__global__ __launch_bounds__(256) void k_attn(const unsigned short* __restrict__ qkvH,
        unsigned short* __restrict__ attnH) {
    __shared__ unsigned short Ks[324 * 40];   // 25.9 KB
    __shared__ unsigned short Vs[324 * 40];   // 25.9 KB
    int bid = blockIdx.x;                     // 8b x 8h x 4pr x 4pc = 1024
    int b = bid >> 7, h = (bid >> 4) & 7, pr = (bid >> 2) & 3, pc = bid & 3;
    int t = threadIdx.x;
    int ty = t >> 4, tx = t & 15;
    const unsigned short* kplane = qkvH + (size_t)(8 + h) * HME;
    const unsigned short* vplane = qkvH + (size_t)(16 + h) * HME;

    // q for own token (global, coalesced) before the barrier
    int tok = (b << 12) + ((pr * 16 + ty) << 6) + (pc * 16 + tx);
    float q[32];
    {
        const uint4* u = (const uint4*)(qkvH + (size_t)h * HME + (size_t)tok * 32);
#pragma unroll
        for (int i = 0; i < 4; ++i) {
            uint4 x4 = u[i];
            unsigned wv[4] = {x4.x, x4.y, x4.z, x4.w};
#pragma unroll
            for (int wj = 0; wj < 4; ++wj) {
                q[i * 8 + wj * 2]     = __uint_as_float(wv[wj] << 16);
                q[i * 8 + wj * 2 + 1] = __uint_as_float(wv[wj] & 0xffff0000u);
            }
        }
    }
    // stage 18x18 halo (wrap-around) K and V
    for (int s = t; s < 324; s += 256) {
        int sr = s / 18, sc = s - sr * 18;
        int gr = (pr * 16 + sr - 1) & 63, gc = (pc * 16 + sc - 1) & 63;
        size_t nt = ((size_t)b << 12) + (gr << 6) + gc;
        const uint4* ksrc = (const uint4*)(kplane + nt * 32);
        const uint4* vsrc = (const uint4*)(vplane + nt * 32);
#pragma unroll
        for (int i = 0; i < 4; ++i) {
            *(uint4*)&Ks[s * 40 + i * 8] = ksrc[i];
            *(uint4*)&Vs[s * 40 + i * 8] = vsrc[i];
        }
    }
    __syncthreads();

    float dots[9];
    int slots[9];
#pragma unroll
    for (int ki = 0; ki < 3; ++ki)
#pragma unroll
        for (int kj = 0; kj < 3; ++kj) {
            int slot = (ty + ki) * 18 + (tx + kj);
            slots[ki * 3 + kj] = slot;
            const unsigned short* kp = &Ks[slot * 40];
            float acc = 0.f;
#pragma unroll
            for (int i = 0; i < 4; ++i) {
                uint4 x4 = *(const uint4*)(kp + i * 8);
                unsigned wv[4] = {x4.x, x4.y, x4.z, x4.w};
#pragma unroll
                for (int wj = 0; wj < 4; ++wj) {
                    acc += __uint_as_float(wv[wj] << 16)         * q[i * 8 + wj * 2];
                    acc += __uint_as_float(wv[wj] & 0xffff0000u) * q[i * 8 + wj * 2 + 1];
                }
            }
            dots[ki * 3 + kj] = acc * 0.17677669529f;
        }
    float m = dots[0];
#pragma unroll
    for (int j = 1; j < 9; ++j) m = fmaxf(m, dots[j]);
    float sum = 0.f;
#pragma unroll
    for (int j = 0; j < 9; ++j) { dots[j] = __expf(dots[j] - m); sum += dots[j]; }
    float inv = 1.f / sum;
    float o[32] = {};
#pragma unroll
    for (int j = 0; j < 9; ++j) {
        float wgt = dots[j] * inv;
        const unsigned short* vp = &Vs[slots[j] * 40];
#pragma unroll
        for (int i = 0; i < 4; ++i) {
            uint4 x4 = *(const uint4*)(vp + i * 8);
            unsigned wv[4] = {x4.x, x4.y, x4.z, x4.w};
#pragma unroll
            for (int wj = 0; wj < 4; ++wj) {
                o[i * 8 + wj * 2]     += wgt * __uint_as_float(wv[wj] << 16);
                o[i * 8 + wj * 2 + 1] += wgt * __uint_as_float(wv[wj] & 0xffff0000u);
            }
        }
    }
    uint4 st[4];
    unsigned* sw = (unsigned*)st;
#pragma unroll
    for (int i = 0; i < 16; ++i)
        sw[i] = (unsigned)f2bf(o[2 * i]) | ((unsigned)f2bf(o[2 * i + 1]) << 16);
    uint4* od = (uint4*)(attnH + (size_t)h * HME + (size_t)tok * 32);
#pragma unroll
    for (int i = 0; i < 4; ++i) od[i] = st[i];
}

// head GEMV via MFMA: Cg[32768,16] = y[32768,256] @ WhT[16,256]^T
__global__ __launch_bounds__(256) void k_headgemv(const unsigned short* __restrict__ y,
        const unsigned short* __restrict__ WhT, float* __restrict__ Cg) {
    int t = threadIdx.x, lane = t & 63, w = t >> 6;
    int m0 = blockIdx.x * 64 + w * 16;
    int fr = lane & 15, kb = (lane >> 4) * 8;
    f32x4 acc = {};
    const unsigned short* aRow = y + (size_t)(m0 + fr) * DIM + kb;
    const unsigned short* bRow = WhT + (size_t)fr * DIM + kb;
#pragma unroll
    for (int k0 = 0; k0 < DIM; k0 += 32) {
        bf16x8 a = *(const bf16x8*)(aRow + k0);
        bf16x8 bfr = *(const bf16x8*)(bRow + k0);
        acc = __builtin_amdgcn_mfma_f32_16x16x32_bf16(a, bfr, acc, 0, 0, 0);
    }
    int col = lane & 15, rowq = (lane >> 4) * 4;
#pragma unroll
    for (int r = 0; r < 4; ++r)
        Cg[(size_t)(m0 + rowq + r) * 16 + col] = acc[r];
}

// out[b,c,n] = cells[b,c,n] + (c>=3 ? Cg[tok,c-3] + bh[c-3] : 0)
__global__ __launch_bounds__(256) void k_assemble(const float* __restrict__ cells,
        const float* __restrict__ Cg, const float* __restrict__ bh,
        float* __restrict__ outp) {
    int idx = blockIdx.x * 256 + threadIdx.x;
    int total = BATCH * CELL_DIM * (NTOK / 4);
    if (idx >= total) return;
    int n4 = idx & 1023;
    int c = (idx >> 10) % CELL_DIM;
    int b = idx / (CELL_DIM * 1024);
    size_t ci = ((size_t)b * CELL_DIM + c) * NTOK + n4 * 4;
    float4 o = *(const float4*)(cells + ci);
    if (c >= PE_IN) {
        int u = c - PE_IN;
        float bias = bh[u];
        size_t tok = (size_t)b * NTOK + n4 * 4;
        o.x += Cg[(tok + 0) * 16 + u] + bias;
        o.y += Cg[(tok + 1) * 16 + u] + bias;
        o.z += Cg[(tok + 2) * 16 + u] + bias;
        o.w += Cg[(tok + 3) * 16 + u] + bias;
    }
    *(float4*)(outp + ci) = o;
}

extern "C" void kernel_launch(void* const* d_in, const int* in_sizes, int n_in,
                              void* d_out, int out_size, void* d_ws, size_t ws_size,
                              hipStream_t stream) {
    const float* cells = (const float*)d_in[0];
    const float* We    = (const float*)d_in[1];
    const float* be    = (const float*)d_in[2];
    const float* ln1_g = (const float*)d_in[3];
    const float* ln1_b = (const float*)d_in[4];
    const float* Wqkv  = (const float*)d_in[5];
    const float* Wo    = (const float*)d_in[6];
    const float* bo    = (const float*)d_in[7];
    const float* ln2_g = (const float*)d_in[8];
    const float* ln2_b = (const float*)d_in[9];
    const float* W1    = (const float*)d_in[10];
    const float* b1    = (const float*)d_in[11];
    const float* W2    = (const float*)d_in[12];
    const float* b2    = (const float*)d_in[13];
    const float* lnh_g = (const float*)d_in[14];
    const float* lnh_b = (const float*)d_in[15];
    const float* Wh    = (const float*)d_in[16];
    const float* bh    = (const float*)d_in[17];
    float* outp = (float*)d_out;

    char* ws = (char*)d_ws;
    unsigned short* x = (unsigned short*)ws;                      // 16.8 MB bf16 residual
    unsigned short* y = (unsigned short*)(ws + 33554432);         // 16.8 MB bf16 LN-out
    unsigned short* scratch = (unsigned short*)(ws + 50331648);   // 67.1 MB: qkvH+attnH / hidden / Cg
    unsigned short* wT = (unsigned short*)(ws + 117440512);       // 3 MB + 8KB transposed weights
    unsigned short* qkvH  = scratch;                              // [3][8][M][32] = 50.3 MB
    unsigned short* attnH = scratch + 24 * HME;                   // [8][M][32]   = 16.8 MB
    unsigned short* hidden = scratch;                             // [M][1024] = 67.1 MB (qkv dead by mlp1)
    float* Cg = (float*)scratch;                                  // reuse after last mlp2

    k_prep<<<dim3(1024, 9), 256, 0, stream>>>(Wqkv, Wo, W1, W2, Wh, wT);
    k_embed<<<M_TOK / 4, 256, 0, stream>>>(cells, We, be, ln1_g, ln1_b, x, y);
    for (int l = 0; l < 2; ++l) {
        const unsigned short* wL = wT + (size_t)l * 786432;
        const float* gN = (l == 0) ? ln1_g + DIM : lnh_g;
        const float* bN = (l == 0) ? ln1_b + DIM : lnh_b;
        k_mgemm<3, 256><<<768, 512, 0, stream>>>(
            y, wL + 0, nullptr, qkvH, M_TOK, 768, 3);
        k_attn<<<1024, 256, 0, stream>>>(qkvH, attnH);
        k_mgemm_ln<1><<<M_TOK / 64, 512, 0, stream>>>(
            attnH, wL + 196608, bo + l * DIM, ln2_g + l * DIM, ln2_b + l * DIM, x, y, DIM);
        k_mgemm<1, 256><<<1024, 512, 0, stream>>>(
            y, wL + 262144, b1 + l * MLP_DIM, hidden, M_TOK, MLP_DIM, 4);
        k_mgemm_ln<0><<<M_TOK / 64, 512, 0, stream>>>(
            hidden, wL + 524288, b2 + l * DIM, gN, bN, x, y, MLP_DIM);
    }
    k_headgemv<<<M_TOK / 64, 256, 0, stream>>>(y, wT + 1572864, Cg);
    k_assemble<<<(BATCH * CELL_DIM * (NTOK / 4) + 255) / 256, 256, 0, stream>>>(cells, Cg, bh, outp);
}

// Round 21
// 318.931 us; speedup vs baseline: 1.0394x; 1.0069x over previous
//
#include <hip/hip_runtime.h>
#include <hip/hip_bf16.h>
#include <math.h>

#define HEADS 8
#define HEAD_DIM 32
#define DIM 256
#define MLP_DIM 1024
#define NTOK 4096
#define BATCH 8
#define M_TOK (BATCH*NTOK)
#define CELL_DIM 15
#define PE_IN 3
#define UPD 12
#define HME ((size_t)M_TOK*32)   // elements per head-plane [tok][32]

typedef __attribute__((ext_vector_type(8))) short bf16x8;
typedef __attribute__((ext_vector_type(4))) float f32x4;

static __device__ __forceinline__ float bf2f(unsigned short u) {
    return __uint_as_float(((unsigned int)u) << 16);
}
static __device__ __forceinline__ unsigned short f2bf(float f) {
    __hip_bfloat16 h = __float2bfloat16(f);
    union { __hip_bfloat16 h; unsigned short u; } cv; cv.h = h; return cv.u;
}
static __device__ __forceinline__ void gload_lds16(const unsigned short* g, unsigned short* l) {
    __builtin_amdgcn_global_load_lds(
        (const __attribute__((address_space(1))) void*)g,
        (__attribute__((address_space(3))) void*)l, 16, 0, 0);
}
// sigmoid-form tanh-approx GELU (max abs err ~3e-4, fine vs 0.105 threshold)
static __device__ __forceinline__ float gelu_fast(float v) {
    return v / (1.f + __expf(-1.59576912f * (v + 0.044715f * v * v * v)));
}

// wave-per-token embed + fused LN1[0]: x(bf16) = cells@We + be + pe ; y = LN(x)
__global__ __launch_bounds__(256) void k_embed(const float* __restrict__ cells,
        const float* __restrict__ We, const float* __restrict__ be,
        const float* __restrict__ g, const float* __restrict__ bln,
        unsigned short* __restrict__ x, unsigned short* __restrict__ y) {
    int wave = threadIdx.x >> 6, lane = threadIdx.x & 63;
    int tok = blockIdx.x * 4 + wave;
    int b = tok >> 12, n = tok & 4095;
    const float* cb = cells + (size_t)b * CELL_DIM * NTOK + n;
    float cv[CELL_DIM];
#pragma unroll
    for (int c = 0; c < CELL_DIM; ++c) cv[c] = cb[c * NTOK];
    int d0 = lane * 4;
    float v[4] = {};
#pragma unroll
    for (int c = 0; c < CELL_DIM; ++c) {
        float4 w4 = *(const float4*)&We[c * DIM + d0];
        v[0] += cv[c] * w4.x; v[1] += cv[c] * w4.y;
        v[2] += cv[c] * w4.z; v[3] += cv[c] * w4.w;
    }
    float4 be4 = *(const float4*)&be[d0];
    float bev[4] = {be4.x, be4.y, be4.z, be4.w};
#pragma unroll
    for (int r = 0; r < 4; ++r) {
        int d = d0 + r;
        float freq = __expf(-0.03597789f * (float)(d & ~1));
        float ph = (float)n * freq;
        float pe = (d & 1) ? __cosf(ph) : __sinf(ph);
        v[r] += bev[r] + pe;
    }
    ushort4 xo;
    xo.x = f2bf(v[0]); xo.y = f2bf(v[1]); xo.z = f2bf(v[2]); xo.w = f2bf(v[3]);
    *(ushort4*)&x[(size_t)tok * DIM + d0] = xo;
    float s = v[0] + v[1] + v[2] + v[3];
    float ss = v[0]*v[0] + v[1]*v[1] + v[2]*v[2] + v[3]*v[3];
#pragma unroll
    for (int off = 32; off; off >>= 1) { s += __shfl_xor(s, off); ss += __shfl_xor(ss, off); }
    float mean = s * (1.f / DIM);
    float rstd = rsqrtf(ss * (1.f / DIM) - mean * mean + 1e-5f);
    float4 g4 = *(const float4*)&g[d0];
    float4 bb4 = *(const float4*)&bln[d0];
    float gv[4] = {g4.x, g4.y, g4.z, g4.w};
    float bbv[4] = {bb4.x, bb4.y, bb4.z, bb4.w};
    ushort4 yo;
    yo.x = f2bf((v[0] - mean) * rstd * gv[0] + bbv[0]);
    yo.y = f2bf((v[1] - mean) * rstd * gv[1] + bbv[1]);
    yo.z = f2bf((v[2] - mean) * rstd * gv[2] + bbv[2]);
    yo.w = f2bf((v[3] - mean) * rstd * gv[3] + bbv[3]);
    *(ushort4*)&y[(size_t)tok * DIM + d0] = yo;
}

// Transpose+convert weights to bf16 [N,K]; seg 8 builds WhT [16x256] (rows 12-15 zero)
__global__ __launch_bounds__(256) void k_prep(const float* __restrict__ Wqkv,
        const float* __restrict__ Wo, const float* __restrict__ W1,
        const float* __restrict__ W2, const float* __restrict__ Wh,
        unsigned short* __restrict__ wT) {
    int seg = blockIdx.y;
    int idx = blockIdx.x * 256 + threadIdx.x;
    if (seg == 8) {
        if (idx >= 16 * 256) return;
        int u = idx >> 8, k = idx & 255;
        wT[1572864 + idx] = (u < UPD) ? f2bf(Wh[(size_t)k * UPD + u]) : (unsigned short)0;
        return;
    }
    int l = seg >> 2, mat = seg & 3;
    const float* src; int kwSh, Nw; size_t ooff;
    switch (mat) {
        case 0: src = Wqkv + (size_t)l * 196608; kwSh = 8;  Nw = 768;  ooff = (size_t)l * 786432 + 0;      break;
        case 1: src = Wo   + (size_t)l * 65536;  kwSh = 8;  Nw = 256;  ooff = (size_t)l * 786432 + 196608; break;
        case 2: src = W1   + (size_t)l * 262144; kwSh = 8;  Nw = 1024; ooff = (size_t)l * 786432 + 262144; break;
        default:src = W2   + (size_t)l * 262144; kwSh = 10; Nw = 256;  ooff = (size_t)l * 786432 + 524288; break;
    }
    int Kw = 1 << kwSh;
    if (idx >= Kw * Nw) return;
    int n = idx >> kwSh, k = idx & (Kw - 1);
    wT[ooff + idx] = f2bf(src[(size_t)k * Nw + n]);
}

// 512-thread (8-wave), tile 128x256, wave owns 64m x 64n (acc[4][4]).
// 3-buffer distance-2 counted-vmcnt pipeline; uniform 3 loads/thread (1 A + 2 B).
// EPI1: gelu_fast(+bias) -> bf16 [M,N] ; EPI3: qkv scatter to head-planes.
template<int EPI, int KT>
__global__ __launch_bounds__(512, 4) void k_mgemm(const unsigned short* __restrict__ A,
        const unsigned short* __restrict__ BT, const float* __restrict__ bias,
        void* __restrict__ Cout, int M, int N, int NT) {
    __shared__ unsigned short As[3][128 * 32];   // 24 KB
    __shared__ unsigned short Bs[3][256 * 32];   // 48 KB
    int bid = blockIdx.x;
    int cpx = gridDim.x >> 3;                   // gridDim.x % 8 == 0
    int sb = (bid & 7) * cpx + (bid >> 3);
    int mt = sb / NT, nt = sb - mt * NT;
    int m0 = mt * 128, n0 = nt * 256;
    int t = threadIdx.x;
    int lane = t & 63, w = t >> 6;
    int wm = (w >> 2) * 64, wn = (w & 3) * 64;
    f32x4 acc[4][4] = {};
    int rA = t >> 2, cgA = (t & 3) ^ ((rA >> 1) & 3);
    const unsigned short* aBase = A + (size_t)(m0 + rA) * KT + cgA * 8;
    int rB0 = t >> 2, cgB0 = (t & 3) ^ ((rB0 >> 1) & 3);
    int c1 = t + 512;
    int rB1 = c1 >> 2, cgB1 = (c1 & 3) ^ ((rB1 >> 1) & 3);
    const unsigned short* b0Base = BT + (size_t)(n0 + rB0) * KT + cgB0 * 8;
    const unsigned short* b1Base = BT + (size_t)(n0 + rB1) * KT + cgB1 * 8;
    int fr = lane & 15, kb8 = lane >> 4;

    auto stage = [&](int buf, int k0) {          // uniform 3 loads / thread
        gload_lds16(aBase + k0,  &As[0][0] + buf * 4096 + t * 8);
        gload_lds16(b0Base + k0, &Bs[0][0] + buf * 8192 + t * 8);
        gload_lds16(b1Base + k0, &Bs[0][0] + buf * 8192 + 4096 + t * 8);
    };
    auto compute = [&](int buf) {
        const unsigned short* a = &As[0][0] + buf * 4096;
        const unsigned short* b = &Bs[0][0] + buf * 8192;
        bf16x8 af[4], bfv[4];
#pragma unroll
        for (int i = 0; i < 4; ++i) {
            int r_ = wm + i * 16 + fr;
            af[i] = *(const bf16x8*)&a[r_ * 32 + ((kb8 ^ ((r_ >> 1) & 3)) << 3)];
        }
#pragma unroll
        for (int j = 0; j < 4; ++j) {
            int r_ = wn + j * 16 + fr;
            bfv[j] = *(const bf16x8*)&b[r_ * 32 + ((kb8 ^ ((r_ >> 1) & 3)) << 3)];
        }
        __builtin_amdgcn_s_setprio(1);
#pragma unroll
        for (int i = 0; i < 4; ++i)
#pragma unroll
            for (int j = 0; j < 4; ++j)   // swapped: D[row=n][col=m]
                acc[i][j] = __builtin_amdgcn_mfma_f32_16x16x32_bf16(bfv[j], af[i], acc[i][j], 0, 0, 0);
        __builtin_amdgcn_s_setprio(0);
    };

    constexpr int NK = KT >> 5;                  // 8 for KT=256
    stage(0, 0);
    stage(1, 32);
    asm volatile("s_waitcnt vmcnt(3)" ::: "memory");   // stage0 landed; stage1 in flight
    __builtin_amdgcn_s_barrier();
    __builtin_amdgcn_sched_barrier(0);
#pragma unroll
    for (int k = 0; k < NK - 1; ++k) {
        if (k + 2 < NK) stage((k + 2) % 3, (k + 2) * 32);
        compute(k % 3);
        __builtin_amdgcn_sched_barrier(0);
        if (k + 2 < NK) asm volatile("s_waitcnt vmcnt(3)" ::: "memory");
        else            asm volatile("s_waitcnt vmcnt(0)" ::: "memory");
        __builtin_amdgcn_s_barrier();
        __builtin_amdgcn_sched_barrier(0);
    }
    compute((NK - 1) % 3);

    int mcol = lane & 15, nq = (lane >> 4) * 4;
#pragma unroll
    for (int i = 0; i < 4; ++i) {
        int m = m0 + wm + i * 16 + mcol;
#pragma unroll
        for (int j = 0; j < 4; ++j) {
            int ng = n0 + wn + j * 16 + nq;
            if (EPI == 3) {
                int type = ng >> 8, rem = ng & 255;
                ushort4 pk;
                pk.x = f2bf(acc[i][j][0]); pk.y = f2bf(acc[i][j][1]);
                pk.z = f2bf(acc[i][j][2]); pk.w = f2bf(acc[i][j][3]);
                *(ushort4*)((unsigned short*)Cout +
                    (size_t)(type * 8 + (rem >> 5)) * HME + (size_t)m * 32 + (rem & 31)) = pk;
            } else {
                float4 b4 = *(const float4*)&bias[ng];
                ushort4 pk;
                pk.x = f2bf(gelu_fast(acc[i][j][0] + b4.x));
                pk.y = f2bf(gelu_fast(acc[i][j][1] + b4.y));
                pk.z = f2bf(gelu_fast(acc[i][j][2] + b4.z));
                pk.w = f2bf(gelu_fast(acc[i][j][3] + b4.w));
                *(ushort4*)((unsigned short*)Cout + (size_t)m * N + ng) = pk;
            }
        }
    }
}

// 512-thread (8-wave) fused residual GEMM + LayerNorm, bf16 residual stream.
// Tile 64x256; wave owns 32 n-cols (acc[4][2]). 3-buffer distance-2; uniform
// 3 loads/thread. Reduction arrays alias As (barrier before reuse).
// ALAYOUT 0: A[M,K] row-major ; 1: A headwise [8][M][32] (K=256)
// x(bf16) = A@BT + bias + x ; y = LN(x; g,b)
template<int ALAYOUT>
__global__ __launch_bounds__(512, 4) void k_mgemm_ln(const unsigned short* __restrict__ A,
        const unsigned short* __restrict__ BT, const float* __restrict__ bias,
        const float* __restrict__ g, const float* __restrict__ bln,
        unsigned short* __restrict__ x, unsigned short* __restrict__ y, int K) {
    __shared__ unsigned short As[3][64 * 32];    // 12 KB (re-used for reductions)
    __shared__ unsigned short Bs[3][256 * 32];   // 48 KB
    float* sred = (float*)&As[0][0];             // [64*8] = 2 KB
    float* ssred = sred + 512;                   // [64*8] = 2 KB
    float* msr = ssred + 512;                    // [64*2] = 0.5 KB
    int t = threadIdx.x;
    int lane = t & 63, w = t >> 6;               // 8 waves, wave owns n-slice w*32
    int wn = w * 32;
    int m0 = blockIdx.x * 64;
    int mloc = lane & 15, nq = (lane >> 4) * 4;

    // prefetch residual x (bf16, ushort4 = 4 elems); issued first -> oldest in vmcnt
    ushort4 xres[4][2];
#pragma unroll
    for (int i = 0; i < 4; ++i) {
        int gm = m0 + i * 16 + mloc;
#pragma unroll
        for (int j = 0; j < 2; ++j)
            xres[i][j] = *(const ushort4*)&x[(size_t)gm * DIM + wn + j * 16 + nq];
    }
    __builtin_amdgcn_sched_barrier(0);           // pin xres loads before stage loads

    f32x4 acc[4][2] = {};
    int rB0 = t >> 2, cgB0 = (t & 3) ^ ((rB0 >> 1) & 3);
    int c1 = t + 512;
    int rB1 = c1 >> 2, cgB1 = (c1 & 3) ^ ((rB1 >> 1) & 3);
    int tA = t & 255;
    int rA = tA >> 2, cgA = (tA & 3) ^ ((rA >> 1) & 3);
    const unsigned short* aBase = (ALAYOUT == 0)
        ? A + (size_t)(m0 + rA) * K + cgA * 8
        : A + (size_t)(m0 + rA) * 32 + cgA * 8;
    const unsigned short* b0Base = BT + (size_t)rB0 * K + cgB0 * 8;
    const unsigned short* b1Base = BT + (size_t)rB1 * K + cgB1 * 8;
    int fr = lane & 15, kb8 = lane >> 4;

    auto stage = [&](int buf, int k0) {          // uniform 3 loads / thread
        unsigned short* as_ = &As[0][0] + buf * 2048;
        unsigned short* bs_ = &Bs[0][0] + buf * 8192;
        gload_lds16(b0Base + k0, bs_ + t * 8);
        gload_lds16(b1Base + k0, bs_ + 4096 + t * 8);
        if (t < 256) {
            const unsigned short* aSrc = (ALAYOUT == 0) ? aBase + k0 : aBase + (size_t)(k0 >> 5) * HME;
            gload_lds16(aSrc, as_ + tA * 8);
        } else {
            gload_lds16(b0Base + k0, bs_ + t * 8);   // benign dup (same addr, same data)
        }
    };
    auto compute = [&](int buf) {
        const unsigned short* as_ = &As[0][0] + buf * 2048;
        const unsigned short* bs_ = &Bs[0][0] + buf * 8192;
        bf16x8 af[4], bfv[2];
#pragma unroll
        for (int i = 0; i < 4; ++i) {
            int r_ = i * 16 + fr;
            af[i] = *(const bf16x8*)&as_[r_ * 32 + ((kb8 ^ ((r_ >> 1) & 3)) << 3)];
        }
#pragma unroll
        for (int j = 0; j < 2; ++j) {
            int rl = wn + j * 16 + fr;           // global B row 0..255
            bfv[j] = *(const bf16x8*)&bs_[rl * 32 + ((kb8 ^ ((rl >> 1) & 3)) << 3)];
        }
        __builtin_amdgcn_s_setprio(1);
#pragma unroll
        for (int i = 0; i < 4; ++i)
#pragma unroll
            for (int j = 0; j < 2; ++j)          // swapped: D[row=n][col=m]
                acc[i][j] = __builtin_amdgcn_mfma_f32_16x16x32_bf16(bfv[j], af[i], acc[i][j], 0, 0, 0);
        __builtin_amdgcn_s_setprio(0);
    };

    int nk = K >> 5;
    stage(0, 0);
    stage(1, 32);
    asm volatile("s_waitcnt vmcnt(3)" ::: "memory");   // xres+stage0 retired, stage1 in flight
    __builtin_amdgcn_s_barrier();
    __builtin_amdgcn_sched_barrier(0);
    int cur = 0;
    for (int k = 0; k < nk - 1; ++k) {
        int pre = k + 2;
        if (pre < nk) {
            int preBuf = cur + 2; if (preBuf >= 3) preBuf -= 3;
            stage(preBuf, pre * 32);
        }
        compute(cur);
        __builtin_amdgcn_sched_barrier(0);
        if (pre < nk) asm volatile("s_waitcnt vmcnt(3)" ::: "memory");
        else          asm volatile("s_waitcnt vmcnt(0)" ::: "memory");
        __builtin_amdgcn_s_barrier();
        __builtin_amdgcn_sched_barrier(0);
        ++cur; if (cur >= 3) cur -= 3;
    }
    compute(cur);
    __syncthreads();                             // before reusing As region for reductions

    // bias + prefetched residual (bf16 unpack), per-row reduce, cross-wave via LDS
#pragma unroll
    for (int i = 0; i < 4; ++i) {
        float s = 0.f, ss = 0.f;
#pragma unroll
        for (int j = 0; j < 2; ++j) {
            int nb = wn + j * 16 + nq;
            float4 b4 = *(const float4*)&bias[nb];
            acc[i][j][0] += b4.x + bf2f(xres[i][j].x);
            acc[i][j][1] += b4.y + bf2f(xres[i][j].y);
            acc[i][j][2] += b4.z + bf2f(xres[i][j].z);
            acc[i][j][3] += b4.w + bf2f(xres[i][j].w);
#pragma unroll
            for (int r = 0; r < 4; ++r) { float v = acc[i][j][r]; s += v; ss += v * v; }
        }
        s += __shfl_xor(s, 16); ss += __shfl_xor(ss, 16);
        s += __shfl_xor(s, 32); ss += __shfl_xor(ss, 32);
        if (lane < 16) {
            int row = i * 16 + lane;
            sred[row * 8 + w] = s;
            ssred[row * 8 + w] = ss;
        }
    }
    __syncthreads();
    if (t < 64) {
        float s = 0.f, ss = 0.f;
#pragma unroll
        for (int q = 0; q < 8; ++q) { s += sred[t * 8 + q]; ss += ssred[t * 8 + q]; }
        float mean = s * (1.f / DIM);
        float var = ss * (1.f / DIM) - mean * mean;
        msr[t * 2] = mean;
        msr[t * 2 + 1] = rsqrtf(var + 1e-5f);
    }
    __syncthreads();
#pragma unroll
    for (int i = 0; i < 4; ++i) {
        int row = i * 16 + mloc;
        int gm = m0 + row;
        float mean = msr[row * 2], rstd = msr[row * 2 + 1];
#pragma unroll
        for (int j = 0; j < 2; ++j) {
            int nb = wn + j * 16 + nq;
            float4 gv4 = *(const float4*)&g[nb];
            float4 bb4 = *(const float4*)&bln[nb];
            ushort4 xo;
            xo.x = f2bf(acc[i][j][0]); xo.y = f2bf(acc[i][j][1]);
            xo.z = f2bf(acc[i][j][2]); xo.w = f2bf(acc[i][j][3]);
            *(ushort4*)&x[(size_t)gm * DIM + nb] = xo;
            ushort4 yv;
            yv.x = f2bf((acc[i][j][0] - mean) * rstd * gv4.x + bb4.x);
            yv.y = f2bf((acc[i][j][1] - mean) * rstd * gv4.y + bb4.y);
            yv.z = f2bf((acc[i][j][2] - mean) * rstd * gv4.z + bb4.z);
            yv.w = f2bf((acc[i][j][3] - mean) * rstd * gv4.w + bb4.w);
            *(ushort4*)&y[(size_t)gm * DIM + nb] = yv;
        }
    }
}

// patch-LDS local 3x3 attention: block = (batch, head, 16x16 token patch).
// 18x18 halo K/V staged in LDS (40-elem padded slots, 16B-aligned), 9x reuse.
__global__ __launch_bounds__(256) void k_attn(const unsigned short* __restrict__ qkvH,
        unsigned short* __restrict__ attnH) {
    __shared__ unsigned short Ks[324 * 40];   // 25.9 KB
    __shared__ unsigned short Vs[324 * 40];   // 25.9 KB
    int bid = blockIdx.x;                     // 8b x 8h x 4pr x 4pc = 1024
    int b = bid >> 7, h = (bid >> 4) & 7, pr = (bid >> 2) & 3, pc = bid & 3;
    int t = threadIdx.x;
    int ty = t >> 4, tx = t & 15;
    const unsigned short* kplane = qkvH + (size_t)(8 + h) * HME;
    const unsigned short* vplane = qkvH + (size_t)(16 + h) * HME;

    // q for own token (global, coalesced) before the barrier
    int tok = (b << 12) + ((pr * 16 + ty) << 6) + (pc * 16 + tx);
    float q[32];
    {
        const uint4* u = (const uint4*)(qkvH + (size_t)h * HME + (size_t)tok * 32);
#pragma unroll
        for (int i = 0; i < 4; ++i) {
            uint4 x4 = u[i];
            unsigned wv[4] = {x4.x, x4.y, x4.z, x4.w};
#pragma unroll
            for (int wj = 0; wj < 4; ++wj) {
                q[i * 8 + wj * 2]     = __uint_as_float(wv[wj] << 16);
                q[i * 8 + wj * 2 + 1] = __uint_as_float(wv[wj] & 0xffff0000u);
            }
        }
    }
    // stage 18x18 halo (wrap-around) K and V
    for (int s = t; s < 324; s += 256) {
        int sr = s / 18, sc = s - sr * 18;
        int gr = (pr * 16 + sr - 1) & 63, gc = (pc * 16 + sc - 1) & 63;
        size_t nt = ((size_t)b << 12) + (gr << 6) + gc;
        const uint4* ksrc = (const uint4*)(kplane + nt * 32);
        const uint4* vsrc = (const uint4*)(vplane + nt * 32);
#pragma unroll
        for (int i = 0; i < 4; ++i) {
            *(uint4*)&Ks[s * 40 + i * 8] = ksrc[i];
            *(uint4*)&Vs[s * 40 + i * 8] = vsrc[i];
        }
    }
    __syncthreads();

    float dots[9];
    int slots[9];
#pragma unroll
    for (int ki = 0; ki < 3; ++ki)
#pragma unroll
        for (int kj = 0; kj < 3; ++kj) {
            int slot = (ty + ki) * 18 + (tx + kj);
            slots[ki * 3 + kj] = slot;
            const unsigned short* kp = &Ks[slot * 40];
            float acc = 0.f;
#pragma unroll
            for (int i = 0; i < 4; ++i) {
                uint4 x4 = *(const uint4*)(kp + i * 8);
                unsigned wv[4] = {x4.x, x4.y, x4.z, x4.w};
#pragma unroll
                for (int wj = 0; wj < 4; ++wj) {
                    acc += __uint_as_float(wv[wj] << 16)         * q[i * 8 + wj * 2];
                    acc += __uint_as_float(wv[wj] & 0xffff0000u) * q[i * 8 + wj * 2 + 1];
                }
            }
            dots[ki * 3 + kj] = acc * 0.17677669529f;
        }
    float m = dots[0];
#pragma unroll
    for (int j = 1; j < 9; ++j) m = fmaxf(m, dots[j]);
    float sum = 0.f;
#pragma unroll
    for (int j = 0; j < 9; ++j) { dots[j] = __expf(dots[j] - m); sum += dots[j]; }
    float inv = 1.f / sum;
    float o[32] = {};
#pragma unroll
    for (int j = 0; j < 9; ++j) {
        float wgt = dots[j] * inv;
        const unsigned short* vp = &Vs[slots[j] * 40];
#pragma unroll
        for (int i = 0; i < 4; ++i) {
            uint4 x4 = *(const uint4*)(vp + i * 8);
            unsigned wv[4] = {x4.x, x4.y, x4.z, x4.w};
#pragma unroll
            for (int wj = 0; wj < 4; ++wj) {
                o[i * 8 + wj * 2]     += wgt * __uint_as_float(wv[wj] << 16);
                o[i * 8 + wj * 2 + 1] += wgt * __uint_as_float(wv[wj] & 0xffff0000u);
            }
        }
    }
    uint4 st[4];
    unsigned* sw = (unsigned*)st;
#pragma unroll
    for (int i = 0; i < 16; ++i)
        sw[i] = (unsigned)f2bf(o[2 * i]) | ((unsigned)f2bf(o[2 * i + 1]) << 16);
    uint4* od = (uint4*)(attnH + (size_t)h * HME + (size_t)tok * 32);
#pragma unroll
    for (int i = 0; i < 4; ++i) od[i] = st[i];
}

// fused head: out[b][3+u][n] = cells[...] + (y@WhT)[tok][u] + bh[u]  (u<12)
// MFMA GEMV per 16-token group; direct scattered stores to output planes.
__global__ __launch_bounds__(256) void k_headfused(const unsigned short* __restrict__ y,
        const unsigned short* __restrict__ WhT, const float* __restrict__ bh,
        const float* __restrict__ cells, float* __restrict__ outp) {
    int t = threadIdx.x, lane = t & 63, w = t >> 6;
    int m0 = blockIdx.x * 64 + w * 16;
    int fr = lane & 15, kb = (lane >> 4) * 8;
    f32x4 acc = {};
    const unsigned short* aRow = y + (size_t)(m0 + fr) * DIM + kb;
    const unsigned short* bRow = WhT + (size_t)fr * DIM + kb;
#pragma unroll
    for (int k0 = 0; k0 < DIM; k0 += 32) {
        bf16x8 a = *(const bf16x8*)(aRow + k0);
        bf16x8 bfr = *(const bf16x8*)(bRow + k0);
        acc = __builtin_amdgcn_mfma_f32_16x16x32_bf16(a, bfr, acc, 0, 0, 0);
    }
    int u = lane & 15, rowq = (lane >> 4) * 4;
    if (u < UPD) {
        float bias = bh[u];
#pragma unroll
        for (int r = 0; r < 4; ++r) {
            int tok = m0 + rowq + r;
            int b = tok >> 12, n = tok & 4095;
            size_t ci = ((size_t)b * CELL_DIM + PE_IN + u) * NTOK + n;
            outp[ci] = cells[ci] + acc[r] + bias;
        }
    }
}

// copy the 3 PE planes: out[b][c][n] = cells[b][c][n] for c<3
__global__ __launch_bounds__(256) void k_copype(const float* __restrict__ cells,
        float* __restrict__ outp) {
    int idx = blockIdx.x * 256 + threadIdx.x;    // BATCH*3*NTOK/4 = 24576
    int n4 = idx & 1023;
    int c = (idx >> 10) % PE_IN;
    int b = idx / (PE_IN * 1024);
    size_t ci = ((size_t)b * CELL_DIM + c) * NTOK + n4 * 4;
    *(float4*)(outp + ci) = *(const float4*)(cells + ci);
}

extern "C" void kernel_launch(void* const* d_in, const int* in_sizes, int n_in,
                              void* d_out, int out_size, void* d_ws, size_t ws_size,
                              hipStream_t stream) {
    const float* cells = (const float*)d_in[0];
    const float* We    = (const float*)d_in[1];
    const float* be    = (const float*)d_in[2];
    const float* ln1_g = (const float*)d_in[3];
    const float* ln1_b = (const float*)d_in[4];
    const float* Wqkv  = (const float*)d_in[5];
    const float* Wo    = (const float*)d_in[6];
    const float* bo    = (const float*)d_in[7];
    const float* ln2_g = (const float*)d_in[8];
    const float* ln2_b = (const float*)d_in[9];
    const float* W1    = (const float*)d_in[10];
    const float* b1    = (const float*)d_in[11];
    const float* W2    = (const float*)d_in[12];
    const float* b2    = (const float*)d_in[13];
    const float* lnh_g = (const float*)d_in[14];
    const float* lnh_b = (const float*)d_in[15];
    const float* Wh    = (const float*)d_in[16];
    const float* bh    = (const float*)d_in[17];
    float* outp = (float*)d_out;

    char* ws = (char*)d_ws;
    unsigned short* x = (unsigned short*)ws;                      // 16.8 MB bf16 residual
    unsigned short* y = (unsigned short*)(ws + 33554432);         // 16.8 MB bf16 LN-out
    unsigned short* scratch = (unsigned short*)(ws + 50331648);   // 67.1 MB: qkvH+attnH / hidden
    unsigned short* wT = (unsigned short*)(ws + 117440512);       // 3 MB + 8KB transposed weights
    unsigned short* qkvH  = scratch;                              // [3][8][M][32] = 50.3 MB
    unsigned short* attnH = scratch + 24 * HME;                   // [8][M][32]   = 16.8 MB
    unsigned short* hidden = scratch;                             // [M][1024] = 67.1 MB (qkv dead by mlp1)

    k_prep<<<dim3(1024, 9), 256, 0, stream>>>(Wqkv, Wo, W1, W2, Wh, wT);
    k_embed<<<M_TOK / 4, 256, 0, stream>>>(cells, We, be, ln1_g, ln1_b, x, y);
    for (int l = 0; l < 2; ++l) {
        const unsigned short* wL = wT + (size_t)l * 786432;
        const float* gN = (l == 0) ? ln1_g + DIM : lnh_g;
        const float* bN = (l == 0) ? ln1_b + DIM : lnh_b;
        k_mgemm<3, 256><<<768, 512, 0, stream>>>(
            y, wL + 0, nullptr, qkvH, M_TOK, 768, 3);
        k_attn<<<1024, 256, 0, stream>>>(qkvH, attnH);
        k_mgemm_ln<1><<<M_TOK / 64, 512, 0, stream>>>(
            attnH, wL + 196608, bo + l * DIM, ln2_g + l * DIM, ln2_b + l * DIM, x, y, DIM);
        k_mgemm<1, 256><<<1024, 512, 0, stream>>>(
            y, wL + 262144, b1 + l * MLP_DIM, hidden, M_TOK, MLP_DIM, 4);
        k_mgemm_ln<0><<<M_TOK / 64, 512, 0, stream>>>(
            hidden, wL + 524288, b2 + l * DIM, gN, bN, x, y, MLP_DIM);
    }
    k_headfused<<<M_TOK / 64, 256, 0, stream>>>(y, wT + 1572864, bh, cells, outp);
    k_copype<<<BATCH * PE_IN * (NTOK / 4) / 256, 256, 0, stream>>>(cells, outp);
}